// Round 17
// baseline (178.576 us; speedup 1.0000x reference)
//
#include <hip/hip_runtime.h>
#include <cstdint>

#define TT 2048
#define NH 16
#define NKV 8
#define HD 128
// 1/sqrt(128) * log2(e)  (softmax computed in exp2 domain)
#define SCALE_L2E 0.12751743f
// static softmax max bound: ||q||=||k||=sqrt(128) (unit rmsnorm weights), RoPE is a
// rotation => |score|*log2(e) <= sqrt(128)*log2(e) = 16.33; margin -> 16.5. P in (0,1].
#define SM_M2 16.5f

typedef unsigned short u16;
typedef unsigned int u32;
typedef u16 u16x8 __attribute__((ext_vector_type(8)));
typedef u32 u32x2 __attribute__((ext_vector_type(2)));
typedef __bf16 bf16x8 __attribute__((ext_vector_type(8)));
typedef float f32x4 __attribute__((ext_vector_type(4)));
typedef float f32x16 __attribute__((ext_vector_type(16)));

__device__ inline u16 f2bf(float x){
  u32 u = __builtin_bit_cast(u32, x);
  u = (u + 0x7fffu + ((u >> 16) & 1u)) >> 16;
  return (u16)u;
}
__device__ inline float bf2f(u16 h){
  return __builtin_bit_cast(float, (u32)h << 16);
}
__device__ inline bf16x8 as_bf(u16x8 v){ return __builtin_bit_cast(bf16x8, v); }

__device__ inline void gl_lds16(const void* g, void* l){
  typedef __attribute__((address_space(1))) const void gv_t;
  typedef __attribute__((address_space(3))) void lv_t;
  __builtin_amdgcn_global_load_lds((gv_t*)g, (lv_t*)l, 16, 0, 0);
}

// ---------------- cast fp32 -> bf16 ----------------
__global__ void cast_f32_bf16(const float* __restrict__ in, u16* __restrict__ out, int n8){
  int i = blockIdx.x * blockDim.x + threadIdx.x;
  if (i < n8){
    const float4* p = (const float4*)(in + (size_t)i * 8);
    float4 a = p[0], b = p[1];
    u16x8 o = { f2bf(a.x), f2bf(a.y), f2bf(a.z), f2bf(a.w),
                f2bf(b.x), f2bf(b.y), f2bf(b.z), f2bf(b.w) };
    *(u16x8*)(out + (size_t)i * 8) = o;
  }
}

// ---------------- transpose + cast: in [R][C] f32 -> out [C][R] bf16 ----------------
__global__ void transpose_cast(const float* __restrict__ in, u16* __restrict__ out, int R, int C){
  __shared__ float tile[64][65];
  int bx = blockIdx.x * 64;  // col base (source)
  int by = blockIdx.y * 64;  // row base (source)
  int tid = threadIdx.x;
  #pragma unroll
  for (int i = 0; i < 4; ++i){
    int idx = i * 256 + tid;           // 0..1023
    int r = idx >> 4, c4 = (idx & 15) * 4;
    float4 v = *(const float4*)&in[(size_t)(by + r) * C + bx + c4];
    tile[r][c4] = v.x; tile[r][c4 + 1] = v.y; tile[r][c4 + 2] = v.z; tile[r][c4 + 3] = v.w;
  }
  __syncthreads();
  #pragma unroll
  for (int i = 0; i < 2; ++i){
    int idx = i * 256 + tid;           // 0..511
    int cc = idx >> 3, s8 = (idx & 7) * 8;
    u16x8 o;
    #pragma unroll
    for (int j = 0; j < 8; ++j) o[j] = f2bf(tile[s8 + j][cc]);
    *(u16x8*)&out[(size_t)(bx + cc) * R + by + s8] = o;
  }
}

// ---------------- 4-phase GEMM: C[M,N] = A[M,K] * B^T  (BM=128, BN=256) ----------------
#define MF16(mmp, af, bf)                                                            \
  do {                                                                               \
    __builtin_amdgcn_s_setprio(1);                                                   \
    _Pragma("unroll") for (int m2 = 0; m2 < 2; m2++)                                 \
    _Pragma("unroll") for (int nn = 0; nn < 4; nn++)                                 \
    _Pragma("unroll") for (int kk = 0; kk < 2; kk++)                                 \
      acc[(mmp)*2 + m2][nn] = __builtin_amdgcn_mfma_f32_16x16x32_bf16(               \
        (af)[m2*2 + kk], (bf)[nn*2 + kk], acc[(mmp)*2 + m2][nn], 0, 0, 0);           \
    __builtin_amdgcn_s_setprio(0);                                                   \
  } while (0)

template<bool F32OUT>
__global__ __launch_bounds__(512, 2) void gemm8ph(const u16* __restrict__ A, const u16* __restrict__ B,
                                                  void* __restrict__ Cv, int Klen,
                                                  int lda, int ldb, int ldc, size_t zstride){
  extern __shared__ u16 smem[];     // 3 bufs x (A 128*64 + B 256*64) u16
  const int tid = threadIdx.x;
  const int wv = tid >> 6, ln = tid & 63;
  const int lg = ln >> 4, l15 = ln & 15;
  const int wr = wv >> 2, wc = wv & 3;          // 2 x 4 wave grid
  const int nbx = gridDim.x;
  const int orig = blockIdx.x + nbx * blockIdx.y;
  const int cpx = (nbx * gridDim.y) >> 3;
  const int swz = (orig & 7) * cpx + (orig >> 3);
  const int m0 = (swz / nbx) * 128, n0 = (swz % nbx) * 256;
  const int Kofs = blockIdx.z * Klen;
  const u16* Ab0 = A + (size_t)m0 * lda + Kofs;
  const u16* Bb0 = B + (size_t)n0 * ldb + Kofs;
  f32x4 acc[4][4] = {};

  auto stageA = [&](int buf, int kt, int c){
    int idx = c * 512 + tid;
    int r = idx >> 3, sl = idx & 7, g = sl ^ (r & 7);
    gl_lds16(Ab0 + (size_t)kt * 64 + (size_t)r * lda + g * 8,
             smem + buf * 24576 + (c * 512 + wv * 64) * 8);
  };
  auto stageB = [&](int buf, int kt, int q){
    int idx = q * 512 + tid;
    int r = idx >> 3, sl = idx & 7, g = sl ^ (r & 7);
    gl_lds16(Bb0 + (size_t)kt * 64 + (size_t)r * ldb + g * 8,
             smem + buf * 24576 + 8192 + (q * 512 + wv * 64) * 8);
  };
  auto ldA = [&](const u16* bufA, int mmp, bf16x8* af){
    #pragma unroll
    for (int m2 = 0; m2 < 2; m2++)
      #pragma unroll
      for (int kk = 0; kk < 2; kk++){
        int ra = wr * 64 + (mmp * 2 + m2) * 16 + l15;
        int sl = (kk * 4 + lg) ^ (ra & 7);
        af[m2 * 2 + kk] = as_bf(*(const u16x8*)&bufA[(ra * 8 + sl) * 8]);
      }
  };
  auto ldB = [&](const u16* bufB, bf16x8* bf){
    #pragma unroll
    for (int nn = 0; nn < 4; nn++)
      #pragma unroll
      for (int kk = 0; kk < 2; kk++){
        int cb = wc * 64 + nn * 16 + l15;
        int sl = (kk * 4 + lg) ^ (cb & 7);
        bf[nn * 2 + kk] = as_bf(*(const u16x8*)&bufB[(cb * 8 + sl) * 8]);
      }
  };

  const int nk = Klen / 64;                     // even, >= 4
  #pragma unroll
  for (int c = 0; c < 2; ++c) stageA(0, 0, c);
  #pragma unroll
  for (int q = 0; q < 4; ++q) stageB(0, 0, q);
  #pragma unroll
  for (int c = 0; c < 2; ++c) stageA(1, 1, c);
  #pragma unroll
  for (int q = 0; q < 4; ++q) stageB(1, 1, q);
  asm volatile("s_waitcnt vmcnt(6)" ::: "memory");
  asm volatile("s_barrier" ::: "memory");

  bf16x8 af[4], bf[8];
  for (int u = 0; u < nk; u += 2){
    const int b0 = u % 3, b1 = (u + 1) % 3, b2 = (u + 2) % 3;
    const u16* A0 = smem + b0 * 24576;  const u16* B0 = A0 + 8192;
    const u16* A1 = smem + b1 * 24576;  const u16* B1 = A1 + 8192;
    const bool st = (u + 2 < nk);
    ldA(A0, 0, af); ldB(B0, bf);
    if (st){ stageA(b2, u + 2, 0); stageA(b2, u + 2, 1); stageB(b2, u + 2, 0); }
    asm volatile("s_barrier" ::: "memory");
    asm volatile("s_waitcnt lgkmcnt(0)" ::: "memory");
    __builtin_amdgcn_sched_barrier(0);
    MF16(0, af, bf);
    asm volatile("s_barrier" ::: "memory");
    ldA(A0, 1, af);
    if (st){ stageB(b2, u + 2, 1); stageB(b2, u + 2, 2); stageB(b2, u + 2, 3); }
    if (st) asm volatile("s_waitcnt vmcnt(6)" ::: "memory");
    else    asm volatile("s_waitcnt vmcnt(0)" ::: "memory");
    asm volatile("s_barrier" ::: "memory");
    asm volatile("s_waitcnt lgkmcnt(0)" ::: "memory");
    __builtin_amdgcn_sched_barrier(0);
    MF16(1, af, bf);
    asm volatile("s_barrier" ::: "memory");
    ldA(A1, 0, af); ldB(B1, bf);
    if (st){ stageA(b0, u + 3, 0); stageA(b0, u + 3, 1); stageB(b0, u + 3, 0); }
    asm volatile("s_barrier" ::: "memory");
    asm volatile("s_waitcnt lgkmcnt(0)" ::: "memory");
    __builtin_amdgcn_sched_barrier(0);
    MF16(0, af, bf);
    asm volatile("s_barrier" ::: "memory");
    ldA(A1, 1, af);
    if (st){ stageB(b0, u + 3, 1); stageB(b0, u + 3, 2); stageB(b0, u + 3, 3); }
    if (st) asm volatile("s_waitcnt vmcnt(6)" ::: "memory");
    asm volatile("s_barrier" ::: "memory");
    asm volatile("s_waitcnt lgkmcnt(0)" ::: "memory");
    __builtin_amdgcn_sched_barrier(0);
    MF16(1, af, bf);
    asm volatile("s_barrier" ::: "memory");
  }
  #pragma unroll
  for (int mm = 0; mm < 4; mm++)
    #pragma unroll
    for (int nn = 0; nn < 4; nn++){
      int grow0 = m0 + wr * 64 + mm * 16 + lg * 4;
      int gcol  = n0 + wc * 64 + nn * 16 + l15;
      #pragma unroll
      for (int r = 0; r < 4; r++){
        float v = acc[mm][nn][r];
        if (F32OUT) ((float*)Cv + blockIdx.z * zstride)[(size_t)(grow0 + r) * ldc + gcol] = v;
        else        ((u16*)Cv)[(size_t)(grow0 + r) * ldc + gcol] = f2bf(v);
      }
    }
}

// ---------------- 1-phase/K-tile GEMM, BN=128, fp32 out (out-projection) ----------------
__global__ __launch_bounds__(512, 2) void gemm_n128(const u16* __restrict__ A, const u16* __restrict__ B,
                                                    float* __restrict__ C, int Klen,
                                                    int lda, int ldb, int ldc){
  extern __shared__ u16 smem[];     // 3 bufs x (A 128*64 + B 128*64) u16 = 96KB
  const int tid = threadIdx.x;
  const int wv = tid >> 6, ln = tid & 63;
  const int lg = ln >> 4, l15 = ln & 15;
  const int wr = wv >> 2, wc = wv & 3;          // 2 x 4 wave grid; per-wave 64x32
  const int nbx = gridDim.x;
  const int orig = blockIdx.x + nbx * blockIdx.y;
  const int cpx = (nbx * gridDim.y) >> 3;
  const int swz = (orig & 7) * cpx + (orig >> 3);
  const int m0 = (swz / nbx) * 128, n0 = (swz % nbx) * 128;
  const u16* Ab0 = A + (size_t)m0 * lda;
  const u16* Bb0 = B + (size_t)n0 * ldb;
  f32x4 acc[4][2] = {};

  auto stage4 = [&](int buf, int kt){
    #pragma unroll
    for (int c = 0; c < 2; ++c){
      int idx = c * 512 + tid;
      int r = idx >> 3, sl = idx & 7, g = sl ^ (r & 7);
      gl_lds16(Ab0 + (size_t)kt * 64 + (size_t)r * lda + g * 8,
               smem + buf * 16384 + (c * 512 + wv * 64) * 8);
    }
    #pragma unroll
    for (int q = 0; q < 2; ++q){
      int idx = q * 512 + tid;
      int r = idx >> 3, sl = idx & 7, g = sl ^ (r & 7);
      gl_lds16(Bb0 + (size_t)kt * 64 + (size_t)r * ldb + g * 8,
               smem + buf * 16384 + 8192 + (q * 512 + wv * 64) * 8);
    }
  };

  const int nk = Klen / 64;
  stage4(0, 0);
  stage4(1, 1);
  asm volatile("s_waitcnt vmcnt(4)" ::: "memory");
  asm volatile("s_barrier" ::: "memory");

  for (int u = 0; u < nk; ++u){
    const u16* A0 = smem + (u % 3) * 16384;
    const u16* B0 = A0 + 8192;
    const bool st = (u + 2 < nk);
    bf16x8 af[8], bf[4];
    #pragma unroll
    for (int mm = 0; mm < 4; mm++)
      #pragma unroll
      for (int kk = 0; kk < 2; kk++){
        int ra = wr * 64 + mm * 16 + l15;
        int sl = (kk * 4 + lg) ^ (ra & 7);
        af[mm * 2 + kk] = as_bf(*(const u16x8*)&A0[(ra * 8 + sl) * 8]);
      }
    #pragma unroll
    for (int nn = 0; nn < 2; nn++)
      #pragma unroll
      for (int kk = 0; kk < 2; kk++){
        int cb = wc * 32 + nn * 16 + l15;
        int sl = (kk * 4 + lg) ^ (cb & 7);
        bf[nn * 2 + kk] = as_bf(*(const u16x8*)&B0[(cb * 8 + sl) * 8]);
      }
    if (st) stage4((u + 2) % 3, u + 2);
    if (st) asm volatile("s_waitcnt vmcnt(4)" ::: "memory");
    else    asm volatile("s_waitcnt vmcnt(0)" ::: "memory");
    asm volatile("s_barrier" ::: "memory");
    asm volatile("s_waitcnt lgkmcnt(0)" ::: "memory");
    __builtin_amdgcn_sched_barrier(0);
    __builtin_amdgcn_s_setprio(1);
    #pragma unroll
    for (int mm = 0; mm < 4; mm++)
      #pragma unroll
      for (int nn = 0; nn < 2; nn++)
        #pragma unroll
        for (int kk = 0; kk < 2; kk++)
          acc[mm][nn] = __builtin_amdgcn_mfma_f32_16x16x32_bf16(
            af[mm * 2 + kk], bf[nn * 2 + kk], acc[mm][nn], 0, 0, 0);
    __builtin_amdgcn_s_setprio(0);
    asm volatile("s_barrier" ::: "memory");
  }
  #pragma unroll
  for (int mm = 0; mm < 4; mm++)
    #pragma unroll
    for (int nn = 0; nn < 2; nn++){
      int grow0 = m0 + wr * 64 + mm * 16 + lg * 4;
      int gcol  = n0 + wc * 32 + nn * 16 + l15;
      #pragma unroll
      for (int r = 0; r < 4; r++)
        C[(size_t)(grow0 + r) * ldc + gcol] = acc[mm][nn][r];
    }
}

// ---------------- RMSNorm + RoPE for Q and K; one wave per (token, head-slot) ----------------
__global__ void rmsnorm_rope(const u16* __restrict__ QKV, const int* __restrict__ pos,
                             const float* __restrict__ qw, const float* __restrict__ kw,
                             u16* __restrict__ Qr, u16* __restrict__ Kr){
  int gw = (blockIdx.x * blockDim.x + threadIdx.x) >> 6;
  int ln = threadIdx.x & 63;
  int t = gw / 24, idx = gw % 24;         // 16 Q heads + 8 K heads
  if (t >= TT) return;
  bool isq = idx < NH;
  int head = isq ? idx : idx - NH;
  const u16* src = QKV + (size_t)t * 4096 + (isq ? head * HD : 2048 + head * HD);
  const float* wgt = isq ? qw : kw;
  float x0 = bf2f(src[ln]), x1 = bf2f(src[ln + 64]);
  float ss = x0 * x0 + x1 * x1;
  #pragma unroll
  for (int off = 32; off; off >>= 1) ss += __shfl_xor(ss, off);
  float r = rsqrtf(ss * (1.0f / 128.0f) + 1e-6f);
  float xn0 = x0 * r * wgt[ln], xn1 = x1 * r * wgt[ln + 64];
  float inv = exp2f(-(float)ln * 0.311430758895690f);  // log2(1e6)/64
  float ang = (float)pos[t] * inv;
  float c = cosf(ang), s = sinf(ang);
  float o0 = xn0 * c - xn1 * s;
  float o1 = xn1 * c + xn0 * s;
  u16* dst = isq ? (Qr + (size_t)t * 2048 + head * HD) : (Kr + (size_t)t * 1024 + head * HD);
  dst[ln]      = f2bf(o0);
  dst[ln + 64] = f2bf(o1);
}

// ---------------- V transpose: QKV[t][3072 + kh*128 + d] -> Vt[kh][d][t] ----------------
__global__ void v_transpose(const u16* __restrict__ QKV, u16* __restrict__ Vt){
  __shared__ u16 tile[64][72];
  int kh = blockIdx.z;
  int d0 = blockIdx.y * 64;
  int t0 = blockIdx.x * 64;
  int tid = threadIdx.x;
  #pragma unroll
  for (int it = 0; it < 2; ++it){
    int idx = it * 256 + tid;          // 0..511
    int tr = idx >> 3, seg = idx & 7;
    *(u16x8*)&tile[tr][seg * 8] =
      *(const u16x8*)(QKV + (size_t)(t0 + tr) * 4096 + 3072 + kh * HD + d0 + seg * 8);
  }
  __syncthreads();
  #pragma unroll
  for (int it = 0; it < 2; ++it){
    int idx = it * 256 + tid;
    int dr = idx >> 3, seg = idx & 7;
    u16x8 v;
    #pragma unroll
    for (int j = 0; j < 8; j++) v[j] = tile[seg * 8 + j][dr];
    *(u16x8*)(Vt + ((size_t)kh * HD + d0 + dr) * 2048 + t0 + seg * 8) = v;
  }
}

// ---------------- causal GQA flash attention: 128-q blocks, shared-fragment waves ----------------
// Grid (16,16): block = 128 q-rows (qc) x head. 8 waves: 4 S (qs,jp), 4 PV (qw2,dp).
// S (qs,jp): QK^T for TWO 32-q blocks (2qs,2qs+1) x 32 toks (jp half), sharing each
// kf read across both q-blocks (8 kf -> 16 MFMA, 2 indep chains) + softmax + P write
// + scalar row-sum accumulation (no ones-MFMA). PV (qw2,dp): P[64q][64t] x V[64t][64d]
// sharing each vf across the two q-blocks (8 pf + 8 vf -> 16 MFMA); owns complete
// O[64q][64d(dp)] -> direct write, no combine. Per-output LDS traffic ~0.64x of R12
// (the measured bottleneck). P single-buffered, R10-style mid s_barrier. Zero-fill of
// masked-but-visible P sub-tiles (jp==1 && D==32) prevents stale reads at diagonals.
// Row-sums: S partials -> Karea (free at end) -> PV epilogue. LDS 80KB => 2 blocks/CU.
__global__ __launch_bounds__(512, 4) void attn(const u16* __restrict__ Qr, const u16* __restrict__ Kr,
                                               const u16* __restrict__ Vt, u16* __restrict__ O){
  extern __shared__ u16 smem[];
  u16* Karea = smem;                   // [2][64tok*128d] u16 (asum area at end)
  u16* Varea = smem + 16384;           // [2][128d*64tok] u16
  u16* Parea = smem + 32768;           // [4 qb][32q][64t] u16 (single buffer)
  const int h = blockIdx.y, kh = h >> 1;
  const int qc = (h < 8) ? blockIdx.x : 15 - blockIdx.x;
  const int tid = threadIdx.x, wv = tid >> 6, ln = tid & 63;
  const bool isS = wv < 4;
  const int role = wv & 3;
  const int q5 = ln & 31, hb = ln >> 5;
  const int nit = 2 * qc + 2;
  const int xr = (q5 & 3) << 1;        // even XOR for P slot swizzle

  auto stage = [&](int i){
    if (i + 1 < nit){                  // K tile i+1 -> buf (i+1)&1
      u16* Kd = Karea + ((i + 1) & 1) * 8192;
      #pragma unroll
      for (int j = 0; j < 2; ++j){
        int lin = j * 512 + tid;
        int tok = lin >> 4, seg = lin & 15;
        gl_lds16(Kr + (size_t)((i + 1) * 64 + tok) * 1024 + kh * HD + (seg ^ (tok & 7)) * 8,
                 Kd + (j * 512 + wv * 64) * 8);
      }
    }
    if (i < nit){                      // V tile i -> buf i&1 (consumed at i+1)
      u16* Vd = Varea + (i & 1) * 8192;
      #pragma unroll
      for (int j = 0; j < 2; ++j){
        int lin = j * 512 + tid;
        int d = lin >> 3, sl = lin & 7;
        gl_lds16(Vt + (size_t)kh * HD * 2048 + (size_t)d * 2048 + i * 64 + (sl ^ (d & 7)) * 8,
                 Vd + (j * 512 + wv * 64) * 8);
      }
    }
  };

  // prestage K[0] into buf 0
  #pragma unroll
  for (int j = 0; j < 2; ++j){
    int lin = j * 512 + tid;
    int tok = lin >> 4, seg = lin & 15;
    gl_lds16(Kr + (size_t)tok * 1024 + kh * HD + (seg ^ (tok & 7)) * 8,
             Karea + (j * 512 + wv * 64) * 8);
  }

  if (isS){
    // ---------------- S role (qs, jp) ----------------
    const int qs = role & 1, jp = role >> 1;
    bf16x8 qf0[8], qf1[8];
    {
      const u16* qp0 = Qr + (size_t)(qc * 128 + qs * 64 + q5) * 2048 + h * HD + hb * 8;
      const u16* qp1 = qp0 + (size_t)32 * 2048;
      #pragma unroll
      for (int s = 0; s < 8; ++s){ qf0[s] = as_bf(*(const u16x8*)(qp0 + s * 16));
                                   qf1[s] = as_bf(*(const u16x8*)(qp1 + s * 16)); }
    }
    float asum0 = 0.f, asum1 = 0.f;
    const int qbase0 = qc * 128 + qs * 64;
    for (int i = 0; i <= nit; ++i){
      __syncthreads();                 // top: K[i], V[i-1], P consumed
      stage(i);
      const int tb = i * 64 + 32 * jp;
      const int D1 = tb - (qbase0 + 32);       // b=1 (later rows, least masked)
      const int D0 = D1 + 32;                  // b=0
      const bool act = (i < nit) && (D1 <= 0);
      f32x16 c0 = {}, c1 = {};
      if (act){
        const u16* Kb = Karea + (i & 1) * 8192;
        const int tokIdx = 32 * jp + q5;
        __builtin_amdgcn_s_setprio(1);
        #pragma unroll
        for (int s = 0; s < 8; ++s){
          int seg = (2 * s + hb) ^ (q5 & 7);
          bf16x8 kf = as_bf(*(const u16x8*)&Kb[tokIdx * 128 + seg * 8]);
          c0 = __builtin_amdgcn_mfma_f32_32x32x16_bf16(kf, qf0[s], c0, 0, 0, 0);
          c1 = __builtin_amdgcn_mfma_f32_32x32x16_bf16(kf, qf1[s], c1, 0, 0, 0);
        }
        __builtin_amdgcn_s_setprio(0);
      }
      asm volatile("s_barrier" ::: "memory");  // mid: PV finished reading P
      if (i < nit){
        // b=1 sub-tile
        if (D1 <= 0){
          const bool diag = (D1 == 0);
          u32 pk[8]; float sum = 0.f;
          #pragma unroll
          for (int j = 0; j < 8; ++j){
            float pv[2];
            #pragma unroll
            for (int e = 0; e < 2; ++e){
              int r = 2 * j + e;
              int tl = (r & 3) + 8 * (r >> 2) + 4 * hb;
              float x = c1[r] * SCALE_L2E - SM_M2;
              if (diag && tl > q5) x = -1e30f;
              pv[e] = exp2f(x);
            }
            sum += pv[0] + pv[1];
            pk[j] = (__builtin_bit_cast(u32, pv[0]) >> 16) |
                    (__builtin_bit_cast(u32, pv[1]) & 0xffff0000u);
          }
          asum1 += sum;
          u16* Pq = Parea + (2 * qs + 1) * 2048 + q5 * 64 + jp * 32;
          #pragma unroll
          for (int m = 0; m < 4; ++m)
            *(u32x2*)&Pq[((hb + 2 * m) ^ xr) * 4] = u32x2{pk[2 * m], pk[2 * m + 1]};
        } else if (jp == 1 && D1 == 32){       // zero-fill: visible to PV, fully masked
          u16* Pq = Parea + (2 * qs + 1) * 2048 + q5 * 64 + jp * 32;
          #pragma unroll
          for (int m = 0; m < 4; ++m)
            *(u32x2*)&Pq[((hb + 2 * m) ^ xr) * 4] = u32x2{0u, 0u};
        }
        // b=0 sub-tile
        if (D0 <= 0){
          const bool diag = (D0 == 0);
          u32 pk[8]; float sum = 0.f;
          #pragma unroll
          for (int j = 0; j < 8; ++j){
            float pv[2];
            #pragma unroll
            for (int e = 0; e < 2; ++e){
              int r = 2 * j + e;
              int tl = (r & 3) + 8 * (r >> 2) + 4 * hb;
              float x = c0[r] * SCALE_L2E - SM_M2;
              if (diag && tl > q5) x = -1e30f;
              pv[e] = exp2f(x);
            }
            sum += pv[0] + pv[1];
            pk[j] = (__builtin_bit_cast(u32, pv[0]) >> 16) |
                    (__builtin_bit_cast(u32, pv[1]) & 0xffff0000u);
          }
          asum0 += sum;
          u16* Pq = Parea + (2 * qs) * 2048 + q5 * 64 + jp * 32;
          #pragma unroll
          for (int m = 0; m < 4; ++m)
            *(u32x2*)&Pq[((hb + 2 * m) ^ xr) * 4] = u32x2{pk[2 * m], pk[2 * m + 1]};
        } else if (jp == 1 && D0 == 32){
          u16* Pq = Parea + (2 * qs) * 2048 + q5 * 64 + jp * 32;
          #pragma unroll
          for (int m = 0; m < 4; ++m)
            *(u32x2*)&Pq[((hb + 2 * m) ^ xr) * 4] = u32x2{0u, 0u};
        }
      }
    }
    // write row-sum partials to Karea (free now): [qb][q5][jp*2+hb] f32
    float* asumL = (float*)smem;
    asumL[(2 * qs + 0) * 128 + q5 * 4 + jp * 2 + hb] = asum0;
    asumL[(2 * qs + 1) * 128 + q5 * 4 + jp * 2 + hb] = asum1;
    __syncthreads();                   // final: asum visible to PV
  } else {
    // ---------------- PV role (qw2, dp) ----------------
    const int qw2 = role & 1, dp = role >> 1;
    f32x16 acc00 = {}, acc01 = {}, acc10 = {}, acc11 = {};   // [b][db], static names
    const int qbase0 = qc * 128 + qw2 * 64;
    for (int i = 0; i <= nit; ++i){
      __syncthreads();                 // top
      stage(i);
      const int tb = (i - 1) * 64;
      const int D1 = tb - (qbase0 + 32);
      const int D0 = D1 + 32;
      const bool v1 = (i >= 1) && (D1 <= 0);
      const bool v0 = (i >= 1) && (D0 <= 0);
      bf16x8 pf1[4], pf0[4];
      if (v1){
        const u16* P1 = Parea + (2 * qw2 + 1) * 2048 + q5 * 64;
        const u16* P0 = Parea + (2 * qw2) * 2048 + q5 * 64;
        #pragma unroll
        for (int ks = 0; ks < 4; ++ks){
          int slot = 8 * (ks >> 1) + ((4 * (ks & 1) + 2 * hb) ^ xr);
          pf1[ks] = as_bf(*(const u16x8*)&P1[slot * 4]);
          if (v0) pf0[ks] = as_bf(*(const u16x8*)&P0[slot * 4]);
        }
        asm volatile("s_waitcnt lgkmcnt(0)" ::: "memory");
        __builtin_amdgcn_sched_barrier(0);
      }
      asm volatile("s_barrier" ::: "memory");  // mid: P reads done before S rewrites
      if (v1){
        const u16* Vb = Varea + ((i - 1) & 1) * 8192;
        __builtin_amdgcn_s_setprio(1);
        #pragma unroll
        for (int ks = 0; ks < 4; ++ks){
          int d0v = dp * 64 + q5;
          int d1v = dp * 64 + 32 + q5;
          bf16x8 vf0 = as_bf(*(const u16x8*)&Vb[d0v * 64 + ((2 * ks + hb) ^ (d0v & 7)) * 8]);
          bf16x8 vf1 = as_bf(*(const u16x8*)&Vb[d1v * 64 + ((2 * ks + hb) ^ (d1v & 7)) * 8]);
          acc10 = __builtin_amdgcn_mfma_f32_32x32x16_bf16(pf1[ks], vf0, acc10, 0, 0, 0);
          acc11 = __builtin_amdgcn_mfma_f32_32x32x16_bf16(pf1[ks], vf1, acc11, 0, 0, 0);
          if (v0){
            acc00 = __builtin_amdgcn_mfma_f32_32x32x16_bf16(pf0[ks], vf0, acc00, 0, 0, 0);
            acc01 = __builtin_amdgcn_mfma_f32_32x32x16_bf16(pf0[ks], vf1, acc01, 0, 0, 0);
          }
        }
        __builtin_amdgcn_s_setprio(0);
      }
    }
    __syncthreads();                   // final: asum partials written by S
    const float* asumL = (const float*)smem;
    #pragma unroll
    for (int b = 0; b < 2; ++b){
      #pragma unroll
      for (int r = 0; r < 16; ++r){
        int qrow = (r & 3) + 8 * (r >> 2) + 4 * hb;
        f32x4 s4 = *(const f32x4*)&asumL[(2 * qw2 + b) * 128 + qrow * 4];
        float rinv = 1.0f / (s4.x + s4.y + s4.z + s4.w);
        int qg = qc * 128 + qw2 * 64 + b * 32 + qrow;
        float o0v = (b ? acc10[r] : acc00[r]) * rinv;
        float o1v = (b ? acc11[r] : acc01[r]) * rinv;
        O[(size_t)qg * 2048 + h * HD + dp * 64 + q5]      = f2bf(o0v);
        O[(size_t)qg * 2048 + h * HD + dp * 64 + 32 + q5] = f2bf(o1v);
      }
    }
  }
}

extern "C" void kernel_launch(void* const* d_in, const int* in_sizes, int n_in,
                              void* d_out, int out_size, void* d_ws, size_t ws_size,
                              hipStream_t stream){
  const int*   positions = (const int*)d_in[0];
  const float* hidden    = (const float*)d_in[1];
  const float* wq        = (const float*)d_in[2];
  const float* wk        = (const float*)d_in[3];
  const float* wv        = (const float*)d_in[4];
  const float* wo        = (const float*)d_in[5];
  const float* qw        = (const float*)d_in[6];
  const float* kw        = (const float*)d_in[7];
  float* out = (float*)d_out;

  char* ws = (char*)d_ws;
  u16* hs   = (u16*)ws; ws += (size_t)2048 * 2048 * 2;
  u16* Wqkv = (u16*)ws; ws += (size_t)4096 * 2048 * 2;   // [4096][2048] = Wq^T | Wk^T | Wv^T
  u16* Wo   = (u16*)ws; ws += (size_t)2048 * 2048 * 2;   // [2048][2048] = wo^T
  u16* QKV  = (u16*)ws; ws += (size_t)2048 * 4096 * 2;   // [T][4096]
  u16* Qr   = (u16*)ws; ws += (size_t)2048 * 2048 * 2;   // [T][16][128]
  u16* Kr   = (u16*)ws; ws += (size_t)2048 * 1024 * 2;   // [T][8][128]
  u16* Vt   = (u16*)ws; ws += (size_t)8 * 128 * 2048 * 2; // [8][128][T]
  u16* O    = (u16*)ws;                                   // [T][2048]

  cast_f32_bf16<<<2048, 256, 0, stream>>>(hidden, hs, 2048 * 2048 / 8);
  transpose_cast<<<dim3(32, 32), 256, 0, stream>>>(wq, Wqkv, 2048, 2048);
  transpose_cast<<<dim3(16, 32), 256, 0, stream>>>(wk, Wqkv + (size_t)2048 * 2048, 2048, 1024);
  transpose_cast<<<dim3(16, 32), 256, 0, stream>>>(wv, Wqkv + (size_t)3072 * 2048, 2048, 1024);
  transpose_cast<<<dim3(32, 32), 256, 0, stream>>>(wo, Wo, 2048, 2048);

  // QKV = hs @ [Wq|Wk|Wv] : M=2048, N=4096, K=2048 ; 256 blocks, 144KB LDS, 1 blk/CU
  gemm8ph<false><<<dim3(16, 16, 1), 512, 147456, stream>>>(hs, Wqkv, QKV, 2048, 2048, 2048, 4096, 0);

  rmsnorm_rope<<<2048 * 24 / 4, 256, 0, stream>>>(QKV, positions, qw, kw, Qr, Kr);
  v_transpose<<<dim3(32, 2, 8), 256, 0, stream>>>(QKV, Vt);

  // attention: 256 blocks x 512 threads, 81920B LDS => 2 blocks/CU
  attn<<<dim3(16, 16), 512, 81920, stream>>>(Qr, Kr, Vt, O);

  // out = O @ wo : BN=128 single-pass, 256 blocks, 96KB LDS, fp32 out (no reduce pass)
  gemm_n128<<<dim3(16, 16), 512, 98304, stream>>>(O, Wo, out, 2048, 2048, 2048, 2048);
}

// Round 18
// 137.151 us; speedup vs baseline: 1.3020x; 1.3020x over previous
//
#include <hip/hip_runtime.h>
#include <cstdint>

#define TT 2048
#define NH 16
#define NKV 8
#define HD 128
// 1/sqrt(128) * log2(e)  (softmax computed in exp2 domain)
#define SCALE_L2E 0.12751743f
// static softmax max bound: ||q||=||k||=sqrt(128) (unit rmsnorm weights), RoPE is a
// rotation => |score|*log2(e) <= sqrt(128)*log2(e) = 16.33; margin -> 16.5. P in (0,1].
#define SM_M2 16.5f

typedef unsigned short u16;
typedef unsigned int u32;
typedef u16 u16x8 __attribute__((ext_vector_type(8)));
typedef u32 u32x2 __attribute__((ext_vector_type(2)));
typedef __bf16 bf16x8 __attribute__((ext_vector_type(8)));
typedef float f32x4 __attribute__((ext_vector_type(4)));
typedef float f32x16 __attribute__((ext_vector_type(16)));

__device__ inline u16 f2bf(float x){
  u32 u = __builtin_bit_cast(u32, x);
  u = (u + 0x7fffu + ((u >> 16) & 1u)) >> 16;
  return (u16)u;
}
__device__ inline float bf2f(u16 h){
  return __builtin_bit_cast(float, (u32)h << 16);
}
__device__ inline bf16x8 as_bf(u16x8 v){ return __builtin_bit_cast(bf16x8, v); }

__device__ inline void gl_lds16(const void* g, void* l){
  typedef __attribute__((address_space(1))) const void gv_t;
  typedef __attribute__((address_space(3))) void lv_t;
  __builtin_amdgcn_global_load_lds((gv_t*)g, (lv_t*)l, 16, 0, 0);
}

// ---------------- merged preprocessing #1: cast hs + 4 weight transposes ----------------
// blocks [0,2048): cast hidden->bf16 ; [2048,3072): wq^T ; [3072,3584): wk^T ;
// [3584,4096): wv^T ; [4096,5120): wo^T. Bodies identical to the previous kernels.
__device__ inline void tc_body(const float* __restrict__ in, u16* __restrict__ out,
                               int R, int C, int bx, int by, int tid, float (*tile)[65]){
  #pragma unroll
  for (int i = 0; i < 4; ++i){
    int idx = i * 256 + tid;
    int r = idx >> 4, c4 = (idx & 15) * 4;
    float4 v = *(const float4*)&in[(size_t)(by + r) * C + bx + c4];
    tile[r][c4] = v.x; tile[r][c4 + 1] = v.y; tile[r][c4 + 2] = v.z; tile[r][c4 + 3] = v.w;
  }
  __syncthreads();
  #pragma unroll
  for (int i = 0; i < 2; ++i){
    int idx = i * 256 + tid;
    int cc = idx >> 3, s8 = (idx & 7) * 8;
    u16x8 o;
    #pragma unroll
    for (int j = 0; j < 8; ++j) o[j] = f2bf(tile[s8 + j][cc]);
    *(u16x8*)&out[(size_t)(bx + cc) * R + by + s8] = o;
  }
}

__global__ void prep_weights(const float* __restrict__ hidden, const float* __restrict__ wq,
                             const float* __restrict__ wk, const float* __restrict__ wv,
                             const float* __restrict__ wo, u16* __restrict__ hs,
                             u16* __restrict__ Wqkv, u16* __restrict__ Wo){
  __shared__ float tile[64][65];
  int b = blockIdx.x, tid = threadIdx.x;
  if (b < 2048){
    int i = b * 256 + tid;
    const float4* p = (const float4*)(hidden + (size_t)i * 8);
    float4 a = p[0], bb = p[1];
    u16x8 o = { f2bf(a.x), f2bf(a.y), f2bf(a.z), f2bf(a.w),
                f2bf(bb.x), f2bf(bb.y), f2bf(bb.z), f2bf(bb.w) };
    *(u16x8*)(hs + (size_t)i * 8) = o;
  } else if (b < 3072){
    int bb = b - 2048;                           // 32 x 32
    tc_body(wq, Wqkv, 2048, 2048, (bb & 31) * 64, (bb >> 5) * 64, tid, tile);
  } else if (b < 3584){
    int bb = b - 3072;                           // 16 x 32
    tc_body(wk, Wqkv + (size_t)2048 * 2048, 2048, 1024, (bb & 15) * 64, (bb >> 4) * 64, tid, tile);
  } else if (b < 4096){
    int bb = b - 3584;
    tc_body(wv, Wqkv + (size_t)3072 * 2048, 2048, 1024, (bb & 15) * 64, (bb >> 4) * 64, tid, tile);
  } else {
    int bb = b - 4096;
    tc_body(wo, Wo, 2048, 2048, (bb & 31) * 64, (bb >> 5) * 64, tid, tile);
  }
}

// ---------------- merged preprocessing #2: rmsnorm+rope and V transpose ----------------
// blocks [0,12288): rmsnorm_rope (4 waves each) ; [12288,12800): v_transpose.
__global__ void prep_qkv(const u16* __restrict__ QKV, const int* __restrict__ pos,
                         const float* __restrict__ qw, const float* __restrict__ kw,
                         u16* __restrict__ Qr, u16* __restrict__ Kr, u16* __restrict__ Vt){
  __shared__ u16 tile[64][72];
  int b = blockIdx.x, tid = threadIdx.x;
  if (b < 12288){
    int gw = (b * 256 + tid) >> 6;
    int ln = tid & 63;
    int t = gw / 24, idx = gw % 24;
    if (t >= TT) return;
    bool isq = idx < NH;
    int head = isq ? idx : idx - NH;
    const u16* src = QKV + (size_t)t * 4096 + (isq ? head * HD : 2048 + head * HD);
    const float* wgt = isq ? qw : kw;
    float x0 = bf2f(src[ln]), x1 = bf2f(src[ln + 64]);
    float ss = x0 * x0 + x1 * x1;
    #pragma unroll
    for (int off = 32; off; off >>= 1) ss += __shfl_xor(ss, off);
    float r = rsqrtf(ss * (1.0f / 128.0f) + 1e-6f);
    float xn0 = x0 * r * wgt[ln], xn1 = x1 * r * wgt[ln + 64];
    float inv = exp2f(-(float)ln * 0.311430758895690f);  // log2(1e6)/64
    float ang = (float)pos[t] * inv;
    float c = cosf(ang), s = sinf(ang);
    float o0 = xn0 * c - xn1 * s;
    float o1 = xn1 * c + xn0 * s;
    u16* dst = isq ? (Qr + (size_t)t * 2048 + head * HD) : (Kr + (size_t)t * 1024 + head * HD);
    dst[ln]      = f2bf(o0);
    dst[ln + 64] = f2bf(o1);
  } else {
    int bb = b - 12288;                          // 512 blocks: (32 t0, 2 d0, 8 kh)
    int t0 = (bb & 31) * 64;
    int d0 = ((bb >> 5) & 1) * 64;
    int kh = bb >> 6;
    #pragma unroll
    for (int it = 0; it < 2; ++it){
      int idx = it * 256 + tid;
      int tr = idx >> 3, seg = idx & 7;
      *(u16x8*)&tile[tr][seg * 8] =
        *(const u16x8*)(QKV + (size_t)(t0 + tr) * 4096 + 3072 + kh * HD + d0 + seg * 8);
    }
    __syncthreads();
    #pragma unroll
    for (int it = 0; it < 2; ++it){
      int idx = it * 256 + tid;
      int dr = idx >> 3, seg = idx & 7;
      u16x8 v;
      #pragma unroll
      for (int j = 0; j < 8; j++) v[j] = tile[seg * 8 + j][dr];
      *(u16x8*)(Vt + ((size_t)kh * HD + d0 + dr) * 2048 + t0 + seg * 8) = v;
    }
  }
}

// ---------------- 4-phase GEMM: C[M,N] = A[M,K] * B^T  (BM=128, BN=256) ----------------
#define MF16(mmp, af, bf)                                                            \
  do {                                                                               \
    __builtin_amdgcn_s_setprio(1);                                                   \
    _Pragma("unroll") for (int m2 = 0; m2 < 2; m2++)                                 \
    _Pragma("unroll") for (int nn = 0; nn < 4; nn++)                                 \
    _Pragma("unroll") for (int kk = 0; kk < 2; kk++)                                 \
      acc[(mmp)*2 + m2][nn] = __builtin_amdgcn_mfma_f32_16x16x32_bf16(               \
        (af)[m2*2 + kk], (bf)[nn*2 + kk], acc[(mmp)*2 + m2][nn], 0, 0, 0);           \
    __builtin_amdgcn_s_setprio(0);                                                   \
  } while (0)

template<bool F32OUT>
__global__ __launch_bounds__(512, 2) void gemm8ph(const u16* __restrict__ A, const u16* __restrict__ B,
                                                  void* __restrict__ Cv, int Klen,
                                                  int lda, int ldb, int ldc, size_t zstride){
  extern __shared__ u16 smem[];     // 3 bufs x (A 128*64 + B 256*64) u16
  const int tid = threadIdx.x;
  const int wv = tid >> 6, ln = tid & 63;
  const int lg = ln >> 4, l15 = ln & 15;
  const int wr = wv >> 2, wc = wv & 3;          // 2 x 4 wave grid
  const int nbx = gridDim.x;
  const int orig = blockIdx.x + nbx * blockIdx.y;
  const int cpx = (nbx * gridDim.y) >> 3;
  const int swz = (orig & 7) * cpx + (orig >> 3);
  const int m0 = (swz / nbx) * 128, n0 = (swz % nbx) * 256;
  const int Kofs = blockIdx.z * Klen;
  const u16* Ab0 = A + (size_t)m0 * lda + Kofs;
  const u16* Bb0 = B + (size_t)n0 * ldb + Kofs;
  f32x4 acc[4][4] = {};

  auto stageA = [&](int buf, int kt, int c){
    int idx = c * 512 + tid;
    int r = idx >> 3, sl = idx & 7, g = sl ^ (r & 7);
    gl_lds16(Ab0 + (size_t)kt * 64 + (size_t)r * lda + g * 8,
             smem + buf * 24576 + (c * 512 + wv * 64) * 8);
  };
  auto stageB = [&](int buf, int kt, int q){
    int idx = q * 512 + tid;
    int r = idx >> 3, sl = idx & 7, g = sl ^ (r & 7);
    gl_lds16(Bb0 + (size_t)kt * 64 + (size_t)r * ldb + g * 8,
             smem + buf * 24576 + 8192 + (q * 512 + wv * 64) * 8);
  };
  auto ldA = [&](const u16* bufA, int mmp, bf16x8* af){
    #pragma unroll
    for (int m2 = 0; m2 < 2; m2++)
      #pragma unroll
      for (int kk = 0; kk < 2; kk++){
        int ra = wr * 64 + (mmp * 2 + m2) * 16 + l15;
        int sl = (kk * 4 + lg) ^ (ra & 7);
        af[m2 * 2 + kk] = as_bf(*(const u16x8*)&bufA[(ra * 8 + sl) * 8]);
      }
  };
  auto ldB = [&](const u16* bufB, bf16x8* bf){
    #pragma unroll
    for (int nn = 0; nn < 4; nn++)
      #pragma unroll
      for (int kk = 0; kk < 2; kk++){
        int cb = wc * 64 + nn * 16 + l15;
        int sl = (kk * 4 + lg) ^ (cb & 7);
        bf[nn * 2 + kk] = as_bf(*(const u16x8*)&bufB[(cb * 8 + sl) * 8]);
      }
  };

  const int nk = Klen / 64;                     // even, >= 4
  #pragma unroll
  for (int c = 0; c < 2; ++c) stageA(0, 0, c);
  #pragma unroll
  for (int q = 0; q < 4; ++q) stageB(0, 0, q);
  #pragma unroll
  for (int c = 0; c < 2; ++c) stageA(1, 1, c);
  #pragma unroll
  for (int q = 0; q < 4; ++q) stageB(1, 1, q);
  asm volatile("s_waitcnt vmcnt(6)" ::: "memory");
  asm volatile("s_barrier" ::: "memory");

  bf16x8 af[4], bf[8];
  for (int u = 0; u < nk; u += 2){
    const int b0 = u % 3, b1 = (u + 1) % 3, b2 = (u + 2) % 3;
    const u16* A0 = smem + b0 * 24576;  const u16* B0 = A0 + 8192;
    const u16* A1 = smem + b1 * 24576;  const u16* B1 = A1 + 8192;
    const bool st = (u + 2 < nk);
    ldA(A0, 0, af); ldB(B0, bf);
    if (st){ stageA(b2, u + 2, 0); stageA(b2, u + 2, 1); stageB(b2, u + 2, 0); }
    asm volatile("s_barrier" ::: "memory");
    asm volatile("s_waitcnt lgkmcnt(0)" ::: "memory");
    __builtin_amdgcn_sched_barrier(0);
    MF16(0, af, bf);
    asm volatile("s_barrier" ::: "memory");
    ldA(A0, 1, af);
    if (st){ stageB(b2, u + 2, 1); stageB(b2, u + 2, 2); stageB(b2, u + 2, 3); }
    if (st) asm volatile("s_waitcnt vmcnt(6)" ::: "memory");
    else    asm volatile("s_waitcnt vmcnt(0)" ::: "memory");
    asm volatile("s_barrier" ::: "memory");
    asm volatile("s_waitcnt lgkmcnt(0)" ::: "memory");
    __builtin_amdgcn_sched_barrier(0);
    MF16(1, af, bf);
    asm volatile("s_barrier" ::: "memory");
    ldA(A1, 0, af); ldB(B1, bf);
    if (st){ stageA(b0, u + 3, 0); stageA(b0, u + 3, 1); stageB(b0, u + 3, 0); }
    asm volatile("s_barrier" ::: "memory");
    asm volatile("s_waitcnt lgkmcnt(0)" ::: "memory");
    __builtin_amdgcn_sched_barrier(0);
    MF16(0, af, bf);
    asm volatile("s_barrier" ::: "memory");
    ldA(A1, 1, af);
    if (st){ stageB(b0, u + 3, 1); stageB(b0, u + 3, 2); stageB(b0, u + 3, 3); }
    if (st) asm volatile("s_waitcnt vmcnt(6)" ::: "memory");
    asm volatile("s_barrier" ::: "memory");
    asm volatile("s_waitcnt lgkmcnt(0)" ::: "memory");
    __builtin_amdgcn_sched_barrier(0);
    MF16(1, af, bf);
    asm volatile("s_barrier" ::: "memory");
  }
  #pragma unroll
  for (int mm = 0; mm < 4; mm++)
    #pragma unroll
    for (int nn = 0; nn < 4; nn++){
      int grow0 = m0 + wr * 64 + mm * 16 + lg * 4;
      int gcol  = n0 + wc * 64 + nn * 16 + l15;
      #pragma unroll
      for (int r = 0; r < 4; r++){
        float v = acc[mm][nn][r];
        if (F32OUT) ((float*)Cv + blockIdx.z * zstride)[(size_t)(grow0 + r) * ldc + gcol] = v;
        else        ((u16*)Cv)[(size_t)(grow0 + r) * ldc + gcol] = f2bf(v);
      }
    }
}

// ---------------- 1-phase/K-tile GEMM, BN=128, fp32 out (out-projection) ----------------
__global__ __launch_bounds__(512, 2) void gemm_n128(const u16* __restrict__ A, const u16* __restrict__ B,
                                                    float* __restrict__ C, int Klen,
                                                    int lda, int ldb, int ldc){
  extern __shared__ u16 smem[];     // 3 bufs x (A 128*64 + B 128*64) u16 = 96KB
  const int tid = threadIdx.x;
  const int wv = tid >> 6, ln = tid & 63;
  const int lg = ln >> 4, l15 = ln & 15;
  const int wr = wv >> 2, wc = wv & 3;          // 2 x 4 wave grid; per-wave 64x32
  const int nbx = gridDim.x;
  const int orig = blockIdx.x + nbx * blockIdx.y;
  const int cpx = (nbx * gridDim.y) >> 3;
  const int swz = (orig & 7) * cpx + (orig >> 3);
  const int m0 = (swz / nbx) * 128, n0 = (swz % nbx) * 128;
  const u16* Ab0 = A + (size_t)m0 * lda;
  const u16* Bb0 = B + (size_t)n0 * ldb;
  f32x4 acc[4][2] = {};

  auto stage4 = [&](int buf, int kt){
    #pragma unroll
    for (int c = 0; c < 2; ++c){
      int idx = c * 512 + tid;
      int r = idx >> 3, sl = idx & 7, g = sl ^ (r & 7);
      gl_lds16(Ab0 + (size_t)kt * 64 + (size_t)r * lda + g * 8,
               smem + buf * 16384 + (c * 512 + wv * 64) * 8);
    }
    #pragma unroll
    for (int q = 0; q < 2; ++q){
      int idx = q * 512 + tid;
      int r = idx >> 3, sl = idx & 7, g = sl ^ (r & 7);
      gl_lds16(Bb0 + (size_t)kt * 64 + (size_t)r * ldb + g * 8,
               smem + buf * 16384 + 8192 + (q * 512 + wv * 64) * 8);
    }
  };

  const int nk = Klen / 64;
  stage4(0, 0);
  stage4(1, 1);
  asm volatile("s_waitcnt vmcnt(4)" ::: "memory");
  asm volatile("s_barrier" ::: "memory");

  for (int u = 0; u < nk; ++u){
    const u16* A0 = smem + (u % 3) * 16384;
    const u16* B0 = A0 + 8192;
    const bool st = (u + 2 < nk);
    bf16x8 af[8], bf[4];
    #pragma unroll
    for (int mm = 0; mm < 4; mm++)
      #pragma unroll
      for (int kk = 0; kk < 2; kk++){
        int ra = wr * 64 + mm * 16 + l15;
        int sl = (kk * 4 + lg) ^ (ra & 7);
        af[mm * 2 + kk] = as_bf(*(const u16x8*)&A0[(ra * 8 + sl) * 8]);
      }
    #pragma unroll
    for (int nn = 0; nn < 2; nn++)
      #pragma unroll
      for (int kk = 0; kk < 2; kk++){
        int cb = wc * 32 + nn * 16 + l15;
        int sl = (kk * 4 + lg) ^ (cb & 7);
        bf[nn * 2 + kk] = as_bf(*(const u16x8*)&B0[(cb * 8 + sl) * 8]);
      }
    if (st) stage4((u + 2) % 3, u + 2);
    if (st) asm volatile("s_waitcnt vmcnt(4)" ::: "memory");
    else    asm volatile("s_waitcnt vmcnt(0)" ::: "memory");
    asm volatile("s_barrier" ::: "memory");
    asm volatile("s_waitcnt lgkmcnt(0)" ::: "memory");
    __builtin_amdgcn_sched_barrier(0);
    __builtin_amdgcn_s_setprio(1);
    #pragma unroll
    for (int mm = 0; mm < 4; mm++)
      #pragma unroll
      for (int nn = 0; nn < 2; nn++)
        #pragma unroll
        for (int kk = 0; kk < 2; kk++)
          acc[mm][nn] = __builtin_amdgcn_mfma_f32_16x16x32_bf16(
            af[mm * 2 + kk], bf[nn * 2 + kk], acc[mm][nn], 0, 0, 0);
    __builtin_amdgcn_s_setprio(0);
    asm volatile("s_barrier" ::: "memory");
  }
  #pragma unroll
  for (int mm = 0; mm < 4; mm++)
    #pragma unroll
    for (int nn = 0; nn < 2; nn++){
      int grow0 = m0 + wr * 64 + mm * 16 + lg * 4;
      int gcol  = n0 + wc * 32 + nn * 16 + l15;
      #pragma unroll
      for (int r = 0; r < 4; r++)
        C[(size_t)(grow0 + r) * ldc + gcol] = acc[mm][nn][r];
    }
}

// ---------------- causal GQA flash attention: P-double-buffered (R12, best measured) ----------------
__global__ __launch_bounds__(512, 4) void attn(const u16* __restrict__ Qr, const u16* __restrict__ Kr,
                                               const u16* __restrict__ Vt, u16* __restrict__ O){
  extern __shared__ u16 smem[];
  u16* Karea = smem;                   // [2][64tok*128d] u16
  u16* Varea = smem + 16384;           // [2][128d*64tok] u16
  u16* Parea = smem + 32768;           // [2buf][4role][32q][32tok] u16
  const int h = blockIdx.y, kh = h >> 1;
  const int qc = (h < 8) ? blockIdx.x : 31 - blockIdx.x;
  const int tid = threadIdx.x, wv = tid >> 6, ln = tid & 63;
  const bool isS = wv < 4;
  const int role = wv & 3;
  const int qw = role & 1, jp = role >> 1;
  const int q5 = ln & 31, hb = ln >> 5;
  const int nit = qc + 1;
  const int xr = (q5 & 3) << 1;        // even XOR for P slot swizzle

  auto stage = [&](int i){
    if (i + 1 < nit){
      u16* Kd = Karea + ((i + 1) & 1) * 8192;
      #pragma unroll
      for (int j = 0; j < 2; ++j){
        int lin = j * 512 + tid;
        int tok = lin >> 4, seg = lin & 15;
        gl_lds16(Kr + (size_t)((i + 1) * 64 + tok) * 1024 + kh * HD + (seg ^ (tok & 7)) * 8,
                 Kd + (j * 512 + wv * 64) * 8);
      }
    }
    if (i < nit){
      u16* Vd = Varea + (i & 1) * 8192;
      #pragma unroll
      for (int j = 0; j < 2; ++j){
        int lin = j * 512 + tid;
        int d = lin >> 3, sl = lin & 7;
        gl_lds16(Vt + (size_t)kh * HD * 2048 + (size_t)d * 2048 + i * 64 + (sl ^ (d & 7)) * 8,
                 Vd + (j * 512 + wv * 64) * 8);
      }
    }
  };

  #pragma unroll
  for (int j = 0; j < 2; ++j){
    int lin = j * 512 + tid;
    int tok = lin >> 4, seg = lin & 15;
    gl_lds16(Kr + (size_t)tok * 1024 + kh * HD + (seg ^ (tok & 7)) * 8,
             Karea + (j * 512 + wv * 64) * 8);
  }

  const u16x8 ones_u = {0x3f80, 0x3f80, 0x3f80, 0x3f80, 0x3f80, 0x3f80, 0x3f80, 0x3f80};
  const bf16x8 onesf = as_bf(ones_u);

  if (isS){
    bf16x8 qf[8];
    {
      const u16* qp = Qr + (size_t)(qc * 64 + qw * 32 + q5) * 2048 + h * HD + hb * 8;
      #pragma unroll
      for (int s = 0; s < 8; ++s) qf[s] = as_bf(*(const u16x8*)(qp + s * 16));
    }
    for (int i = 0; i <= nit; ++i){
      __syncthreads();
      stage(i);
      const int t = 2 * i + jp;
      const int D0 = 32 * t - 64 * qc - 32 * qw;
      const bool act = (i < nit) && (D0 <= 0);
      if (act){
        const u16* Kb = Karea + (i & 1) * 8192;
        const int tokIdx = 32 * jp + q5;
        f32x16 ca = {}, cb = {};
        __builtin_amdgcn_s_setprio(1);
        #pragma unroll
        for (int s = 0; s < 4; ++s){
          int seg = (2 * s + hb) ^ (q5 & 7);
          bf16x8 kf = as_bf(*(const u16x8*)&Kb[tokIdx * 128 + seg * 8]);
          ca = __builtin_amdgcn_mfma_f32_32x32x16_bf16(kf, qf[s], ca, 0, 0, 0);
        }
        #pragma unroll
        for (int s = 4; s < 8; ++s){
          int seg = (2 * s + hb) ^ (q5 & 7);
          bf16x8 kf = as_bf(*(const u16x8*)&Kb[tokIdx * 128 + seg * 8]);
          cb = __builtin_amdgcn_mfma_f32_32x32x16_bf16(kf, qf[s], cb, 0, 0, 0);
        }
        __builtin_amdgcn_s_setprio(0);
        f32x16 c = ca + cb;
        const bool diag = (D0 == 0);
        u32 pk[8];
        #pragma unroll
        for (int j = 0; j < 8; ++j){
          float pv[2];
          #pragma unroll
          for (int e = 0; e < 2; ++e){
            int r = 2 * j + e;
            int tok = (r & 3) + 8 * (r >> 2) + 4 * hb;
            float x = c[r] * SCALE_L2E - SM_M2;
            if (diag && tok > q5) x = -1e30f;
            pv[e] = exp2f(x);
          }
          pk[j] = (__builtin_bit_cast(u32, pv[0]) >> 16) |
                  (__builtin_bit_cast(u32, pv[1]) & 0xffff0000u);
        }
        u16* Pq = Parea + (i & 1) * 4096 + role * 1024 + q5 * 32;
        *(u32x2*)&Pq[((hb + 0) ^ xr) * 4] = u32x2{pk[0], pk[1]};
        *(u32x2*)&Pq[((hb + 2) ^ xr) * 4] = u32x2{pk[2], pk[3]};
        *(u32x2*)&Pq[((hb + 4) ^ xr) * 4] = u32x2{pk[4], pk[5]};
        *(u32x2*)&Pq[((hb + 6) ^ xr) * 4] = u32x2{pk[6], pk[7]};
      }
    }
    __syncthreads();
    __syncthreads();
  } else {
    f32x16 acc[4] = {};
    f32x16 asum = {};
    for (int i = 0; i <= nit; ++i){
      __syncthreads();
      stage(i);
      const int t = 2 * (i - 1) + jp;
      const int D0 = 32 * t - 64 * qc - 32 * qw;
      const bool act = (i >= 1) && (D0 <= 0);
      if (act){
        const u16* Pq = Parea + ((i - 1) & 1) * 4096 + role * 1024 + q5 * 32;
        bf16x8 pf0 = as_bf(*(const u16x8*)&Pq[((2 * hb + 0) ^ xr) * 4]);
        bf16x8 pf1 = as_bf(*(const u16x8*)&Pq[((2 * hb + 4) ^ xr) * 4]);
        const u16* Vb = Varea + ((i - 1) & 1) * 8192;
        __builtin_amdgcn_s_setprio(1);
        asum = __builtin_amdgcn_mfma_f32_32x32x16_bf16(pf0, onesf, asum, 0, 0, 0);
        asum = __builtin_amdgcn_mfma_f32_32x32x16_bf16(pf1, onesf, asum, 0, 0, 0);
        #pragma unroll
        for (int dblk = 0; dblk < 4; ++dblk){
          int d = dblk * 32 + q5;
          bf16x8 v0 = as_bf(*(const u16x8*)&Vb[d * 64 + ((4 * jp + 0 + hb) ^ (d & 7)) * 8]);
          bf16x8 v1 = as_bf(*(const u16x8*)&Vb[d * 64 + ((4 * jp + 2 + hb) ^ (d & 7)) * 8]);
          acc[dblk] = __builtin_amdgcn_mfma_f32_32x32x16_bf16(pf0, v0, acc[dblk], 0, 0, 0);
          acc[dblk] = __builtin_amdgcn_mfma_f32_32x32x16_bf16(pf1, v1, acc[dblk], 0, 0, 0);
        }
        __builtin_amdgcn_s_setprio(0);
      }
    }
    __syncthreads();
    float* Ls  = (float*)smem;
    float* LsS = (float*)smem + 8192;
    if (jp == 1){
      #pragma unroll
      for (int dblk = 0; dblk < 4; ++dblk)
        #pragma unroll
        for (int r = 0; r < 16; ++r){
          int qrow = (r & 3) + 8 * (r >> 2) + 4 * hb;
          Ls[qw * 4096 + qrow * 128 + dblk * 32 + q5] = acc[dblk][r];
        }
      if (q5 == 0){
        #pragma unroll
        for (int r = 0; r < 16; ++r){
          int qrow = (r & 3) + 8 * (r >> 2) + 4 * hb;
          LsS[qw * 32 + qrow] = asum[r];
        }
      }
    }
    __syncthreads();
    if (jp == 0){
      #pragma unroll
      for (int r = 0; r < 16; ++r){
        int qrow = (r & 3) + 8 * (r >> 2) + 4 * hb;
        float rs = 1.0f / (asum[r] + LsS[qw * 32 + qrow]);
        int qg = qc * 64 + qw * 32 + qrow;
        #pragma unroll
        for (int dblk = 0; dblk < 4; ++dblk){
          float o = (acc[dblk][r] + Ls[qw * 4096 + qrow * 128 + dblk * 32 + q5]) * rs;
          O[(size_t)qg * 2048 + h * HD + dblk * 32 + q5] = f2bf(o);
        }
      }
    }
  }
}

extern "C" void kernel_launch(void* const* d_in, const int* in_sizes, int n_in,
                              void* d_out, int out_size, void* d_ws, size_t ws_size,
                              hipStream_t stream){
  const int*   positions = (const int*)d_in[0];
  const float* hidden    = (const float*)d_in[1];
  const float* wq        = (const float*)d_in[2];
  const float* wk        = (const float*)d_in[3];
  const float* wv        = (const float*)d_in[4];
  const float* wo        = (const float*)d_in[5];
  const float* qw        = (const float*)d_in[6];
  const float* kw        = (const float*)d_in[7];
  float* out = (float*)d_out;

  char* ws = (char*)d_ws;
  u16* hs   = (u16*)ws; ws += (size_t)2048 * 2048 * 2;
  u16* Wqkv = (u16*)ws; ws += (size_t)4096 * 2048 * 2;   // [4096][2048] = Wq^T | Wk^T | Wv^T
  u16* Wo   = (u16*)ws; ws += (size_t)2048 * 2048 * 2;   // [2048][2048] = wo^T
  u16* QKV  = (u16*)ws; ws += (size_t)2048 * 4096 * 2;   // [T][4096]
  u16* Qr   = (u16*)ws; ws += (size_t)2048 * 2048 * 2;   // [T][16][128]
  u16* Kr   = (u16*)ws; ws += (size_t)2048 * 1024 * 2;   // [T][8][128]
  u16* Vt   = (u16*)ws; ws += (size_t)8 * 128 * 2048 * 2; // [8][128][T]
  u16* O    = (u16*)ws;                                   // [T][2048]

  // merged preprocessing: cast + 4 weight transposes in ONE launch
  prep_weights<<<5120, 256, 0, stream>>>(hidden, wq, wk, wv, wo, hs, Wqkv, Wo);

  // QKV = hs @ [Wq|Wk|Wv] : M=2048, N=4096, K=2048 ; 256 blocks, 144KB LDS, 1 blk/CU
  gemm8ph<false><<<dim3(16, 16, 1), 512, 147456, stream>>>(hs, Wqkv, QKV, 2048, 2048, 2048, 4096, 0);

  // merged rmsnorm+rope and V transpose in ONE launch
  prep_qkv<<<12800, 256, 0, stream>>>(QKV, positions, qw, kw, Qr, Kr, Vt);

  // attention: 512 blocks x 512 threads, 81920B LDS => 2 blocks/CU
  attn<<<dim3(32, 16), 512, 81920, stream>>>(Qr, Kr, Vt, O);

  // out = O @ wo : BN=128 single-pass, 256 blocks, 96KB LDS, fp32 out (no reduce pass)
  gemm_n128<<<dim3(16, 16), 512, 98304, stream>>>(O, Wo, out, 2048, 2048, 2048, 2048);
}